// Round 15
// baseline (338.717 us; speedup 1.0000x reference)
//
#include <hip/hip_runtime.h>
#include <hip/hip_bf16.h>
#include <stdint.h>

#define HIDDEN 1024
#define FFN    4096
#define NROWS  8192   // 4*2048
#define TOPK_K 32
#define NCAND  40
#define MU     3e-3f  // band >= 2.5x max fp16-approx error (1.2e-3)
#define KC     384    // OpenBLAS SGEMM_DEFAULT_Q (verified rounds 4-14)
#define CCAP   256    // candidate capacity (survivors ~125 +- 11; validated R5-R14)
#define T0     1.25f  // pre-filter threshold: 7.7 sigma below |h|_(40)

#define BM 128
#define BN 128
#define BK 32
#define NT (HIDDEN / BK)      // 32 K-tiles
#define ABUF (BM * BK)        // f16 elems per ring slot (A only) = 8 KB

typedef _Float16 f16;
typedef __attribute__((ext_vector_type(8))) _Float16 f16x8;
typedef __attribute__((ext_vector_type(4))) _Float16 f16x4;
typedef __attribute__((ext_vector_type(4))) float f32x4;
typedef unsigned long long u64;
typedef unsigned int u32;

__device__ __forceinline__ void async_copy16(const void* g, void* l) {
  __builtin_amdgcn_global_load_lds((void __attribute__((address_space(1)))*)(g),
                                   (void __attribute__((address_space(3)))*)(l),
                                   16, 0, 0);
}

// ------------------------------------------------- fused preprocessing:
// blocks [0,2048): fp32->fp16 convert of x and W1 (grid-stride)
// blocks [2048,6144): W2 transpose tile -> f16 [4096][1024]
__global__ void prep_kernel(const float* __restrict__ x, const float* __restrict__ W1,
                            const float* __restrict__ W2,
                            f16* __restrict__ xh, f16* __restrict__ wh,
                            f16* __restrict__ w2t) {
  const int tid = threadIdx.x;
  if (blockIdx.x < 2048) {
    const int n4x = NROWS * HIDDEN / 4;
    const int n4w = FFN * HIDDEN / 4;
    int i = blockIdx.x * 256 + tid;
    int stride = 2048 * 256;
    for (; i < n4x + n4w; i += stride) {
      const float4 v = (i < n4x) ? reinterpret_cast<const float4*>(x)[i]
                                 : reinterpret_cast<const float4*>(W1)[i - n4x];
      f16x4 o = {(f16)v.x, (f16)v.y, (f16)v.z, (f16)v.w};
      if (i < n4x) reinterpret_cast<f16x4*>(xh)[i] = o;
      else         reinterpret_cast<f16x4*>(wh)[i - n4x] = o;
    }
  } else {
    __shared__ float tile[32][33];
    const int b = blockIdx.x - 2048;
    const int bx = (b & 127) * 32;          // FFN
    const int by = (b >> 7) * 32;           // HIDDEN
    const int tx = tid & 31, ty = tid >> 5; // 32 x 8
#pragma unroll
    for (int r = 0; r < 32; r += 8)
      tile[ty + r][tx] = W2[(size_t)(by + ty + r) * FFN + bx + tx];
    __syncthreads();
#pragma unroll
    for (int r = 0; r < 32; r += 8)
      w2t[(size_t)(bx + ty + r) * HIDDEN + by + tx] = (f16)tile[tx][ty + r];
  }
}

// ------------------------------------------------- GEMM1 + fused T0 filter
// fp16 single-product, 128x128 tile. A: 3-slot LDS ring (8 KB/slot) via
// global_load_lds with chunk-swizzle (verified 0-conflict R9-R14).
// B: DIRECT global->VGPR fragments (perfectly coalesced 16-row x 64B
// pattern, L2-resident panel), double-buffered one iter ahead in two named
// reg sets (no LDS traffic for B at all). LDS port load per block-iter
// drops 48KB -> 24KB (the measured R14 bottleneck). Counted waits:
// newer-than-A(t) at the wait = A(t+1)2+B(t)4+A(t+2)2+B(t+1)4 = vmcnt(12).
__global__ __launch_bounds__(256, 4)
void gemm_topk_fused(const f16* __restrict__ xh,
                     const f16* __restrict__ wh,
                     const float* __restrict__ b1,
                     u64* __restrict__ ckeys, float* __restrict__ cvals,
                     int* __restrict__ cnt) {
  __shared__ __align__(16) f16 smem[3][ABUF];   // 24 KB

  const int tid = threadIdx.x;
  const int rowBase = blockIdx.x * BM;
  const int colBase = blockIdx.y * BN;

  const int wid = tid >> 6, lane = tid & 63;
  const int wr = (wid >> 1) * 64;       // wave row offset in tile
  const int wc = (wid & 1) * 64;        // wave col offset in tile
  const int lr = lane & 15;
  const int kch = lane >> 4;            // k-chunk 0..3 (8 f16 each)

  // A staging: thread covers 16B; dest LDS = tid*16 bytes (linear, required)
  const int r0 = tid >> 2;              // 0..63
  const int r1 = r0 + 64;               // 64..127
  const int c = tid & 3;
  const int off0 = r0 * BK + c * 8;     // == tid*8 f16
  const int off1 = r1 * BK + c * 8;
  const int sw = (c ^ ((r0 >> 1) & 3)) * 8;   // inverse swizzle

  const u32 gA0 = (u32)((rowBase + r0) * HIDDEN + sw);
  const u32 gA1 = (u32)((rowBase + r1) * HIDDEN + sw);

  // B fragment offsets (u32, direct global loads, no swizzle)
  u32 gBr[4];
#pragma unroll
  for (int n = 0; n < 4; ++n)
    gBr[n] = (u32)((colBase + wc + n * 16 + lr) * HIDDEN + kch * 8);

  f32x4 acc[4][4];
  const f32x4 zero4 = {0.f, 0.f, 0.f, 0.f};
#pragma unroll
  for (int m = 0; m < 4; ++m)
#pragma unroll
    for (int n = 0; n < 4; ++n) acc[m][n] = zero4;

  // swizzled A read offsets (row-dependent chunk XOR)
  int roffA[4];
#pragma unroll
  for (int m = 0; m < 4; ++m) {
    int row = wr + m * 16 + lr;
    roffA[m] = row * BK + ((kch ^ ((row >> 1) & 3)) << 3);
  }

  f16x8 b0[4], b1f[4];

#define STAGE(slot, kb)                                       \
  do {                                                        \
    f16* sA_ = smem[slot];                                    \
    async_copy16(xh + gA0 + (kb), sA_ + off0);                \
    async_copy16(xh + gA1 + (kb), sA_ + off1);                \
  } while (0)

#define LOADB(dst, kb)                                        \
  do {                                                        \
    _Pragma("unroll")                                         \
    for (int n = 0; n < 4; ++n)                               \
      dst[n] = *(const f16x8*)(wh + gBr[n] + (kb));           \
  } while (0)

#define COMPUTE(slot, B)                                      \
  do {                                                        \
    const f16* sA_ = smem[slot];                              \
    f16x8 a[4];                                               \
    _Pragma("unroll")                                         \
    for (int m = 0; m < 4; ++m) a[m] = *(const f16x8*)(sA_ + roffA[m]); \
    _Pragma("unroll")                                         \
    for (int m = 0; m < 4; ++m)                               \
      _Pragma("unroll")                                       \
      for (int n = 0; n < 4; ++n)                             \
        acc[m][n] = __builtin_amdgcn_mfma_f32_16x16x32_f16(a[m], B[n], acc[m][n], 0, 0, 0); \
  } while (0)

#define ITER(t, BCUR, BNXT)                                   \
  do {                                                        \
    STAGE((t + 2) % 3, (t + 2) * BK);                         \
    LOADB(BNXT, (t + 1) * BK);                                \
    asm volatile("s_waitcnt vmcnt(12)\n\ts_barrier" ::: "memory"); \
    COMPUTE((t) % 3, BCUR);                                   \
    asm volatile("s_barrier" ::: "memory");                   \
  } while (0)

  // prologue: A(0), A(1), B(0)
  STAGE(0, 0);
  STAGE(1, BK);
  LOADB(b0, 0);

  // main loop t = 0..NT-3 (unrolled by 2 for static B-buffer parity)
  for (int t = 0; t < NT - 2; t += 2) {
    ITER(t, b0, b1f);
    ITER(t + 1, b1f, b0);
  }
  // t = NT-2 (even -> b0 current): B(29) retired; newer than A(30):
  // A(31)2 + B(30)4 + B(31)4 = 10
  LOADB(b1f, (NT - 1) * BK);
  asm volatile("s_waitcnt vmcnt(10)\n\ts_barrier" ::: "memory");
  COMPUTE((NT - 2) % 3, b0);
  asm volatile("s_barrier" ::: "memory");
  // t = NT-1: newer than A(31): B(31)4 (B(30) retired)
  asm volatile("s_waitcnt vmcnt(4)\n\ts_barrier" ::: "memory");
  COMPUTE((NT - 1) % 3, b1f);
#undef STAGE
#undef LOADB
#undef COMPUTE
#undef ITER

  // epilogue: bias + T0 filter + compact append
  // C/D layout (verified m89/m91): col = lane&15, row = (lane>>4)*4 + reg
  const int ccol = lane & 15;
  const int crow = (lane >> 4) * 4;
#pragma unroll
  for (int n = 0; n < 4; ++n) {
    int col = colBase + wc + n * 16 + ccol;
    float bias = b1[col];
    u32 inv = 0xFFFFFFFFu - (u32)col;
#pragma unroll
    for (int m = 0; m < 4; ++m) {
      int rowb = rowBase + wr + m * 16 + crow;
#pragma unroll
      for (int j = 0; j < 4; ++j) {
        float val = acc[m][n][j] + bias;
        if (fabsf(val) >= T0) {
          int row = rowb + j;
          int pos = atomicAdd(&cnt[row], 1);
          if (pos < CCAP) {
            ckeys[(size_t)row * CCAP + pos] =
                ((u64)__float_as_uint(fabsf(val)) << 32) | (u64)inv;
            cvals[(size_t)row * CCAP + pos] = val;
          }
        }
      }
    }
  }
}

// ------------------------------------------------- per-row select + adjudicate + gather (fused)
// Rank-select top-40, verified round-4..14 adjudication (MU-band classify,
// OpenBLAS kc=384 fp32-chain emulation, cube), index-ascending order, then
// the sparse gather from fp16 W2T.
__global__ __launch_bounds__(256)
void topk_scatter(const u64* __restrict__ ckeys, const float* __restrict__ cvals,
                  const int* __restrict__ cnt,
                  const float* __restrict__ x, const float* __restrict__ W1,
                  const float* __restrict__ b1,
                  const f16* __restrict__ w2t, const float* __restrict__ b2,
                  float* __restrict__ out) {
  const int row = blockIdx.x;
  const int tid = threadIdx.x;

  __shared__ u64 k_lds[CCAP];
  __shared__ float v_lds[CCAP];
  __shared__ float sval[NCAND];
  __shared__ int   sidx[NCAND];
  __shared__ int   sS, sB;
  __shared__ float sv32[NCAND];
  __shared__ int   fidx[TOPK_K];
  __shared__ float fcoef[TOPK_K];
  __shared__ int   sIdx[TOPK_K];     // index-ascending
  __shared__ float sCf[TOPK_K];

  int c = cnt[row];
  c = c < CCAP ? c : CCAP;
  if (tid < c) {
    k_lds[tid] = ckeys[(size_t)row * CCAP + tid];
    v_lds[tid] = cvals[(size_t)row * CCAP + tid];
  }
  if (tid < NCAND) { sval[tid] = 0.f; sidx[tid] = 0x7FFF0000 + tid; }
  __syncthreads();

  // parallel rank-select (keys unique -> strict order)
  if (tid < c) {
    const u64 mine = k_lds[tid];
    int rank = 0;
    for (int j2 = 0; j2 < c; ++j2)
      rank += (k_lds[j2] > mine) ? 1 : 0;
    if (rank < NCAND) {
      sval[rank] = v_lds[tid];
      sidx[rank] = (int)(0xFFFFFFFFu - (u32)(mine & 0xFFFFFFFFull));
    }
  }
  __syncthreads();

  // classify: sure-in prefix (> t+MU) vs boundary band [t-MU, t+MU]
  if (tid == 0) {
    float t = fabsf(sval[TOPK_K - 1]);
    int s = 0;
    while (s < TOPK_K - 1 && fabsf(sval[s]) > t + MU) ++s;
    int e = s;
    while (e < NCAND && fabsf(sval[e]) >= t - MU) ++e;
    sS = s;
    sB = e - s;       // >= 1 always (slot 31 is in the band)
  }
  __syncthreads();
  const int s = sS, nb = sB;

  // OpenBLAS-sgemm rounding emulation for boundary candidates
  if (nb > 1 && tid < nb) {
    const int fi = sidx[s + tid];
    const float* xr = x + (size_t)row * HIDDEN;
    const float* w1r = W1 + (size_t)fi * HIDDEN;
    float p0 = 0.0f, p1 = 0.0f, p2 = 0.0f;
    for (int k2 = 0; k2 < KC; ++k2)
      p0 = __builtin_fmaf(xr[k2], w1r[k2], p0);
    for (int k2 = KC; k2 < 2 * KC; ++k2)
      p1 = __builtin_fmaf(xr[k2], w1r[k2], p1);
    for (int k2 = 2 * KC; k2 < HIDDEN; ++k2)
      p2 = __builtin_fmaf(xr[k2], w1r[k2], p2);
    float acc = __fadd_rn(__fadd_rn(p0, p1), p2);   // C += panel merges
    sv32[tid] = __fadd_rn(acc, b1[fi]);
  }
  __syncthreads();

  if (tid == 0) {
    for (int k2 = 0; k2 < TOPK_K; ++k2) {
      fidx[k2] = sidx[k2];
      float hv = sval[k2];
      fcoef[k2] = __fmul_rn(__fmul_rn(hv, hv), hv);
    }
    if (nb > 1) {
      int need = TOPK_K - s;
      u64 used = 0;
      for (int n = 0; n < need; ++n) {
        int bestc = -1;
        u64 bestk = 0;
        for (int c2 = 0; c2 < nb; ++c2) {
          if (used & (1ull << c2)) continue;
          unsigned abv = __float_as_uint(fabsf(sv32[c2]));
          u64 kk2 = ((u64)abv << 32) | (u64)(0xFFFFFFFFu - (unsigned)sidx[s + c2]);
          if (bestc < 0 || kk2 > bestk) { bestk = kk2; bestc = c2; }
        }
        used |= 1ull << bestc;
        float hv = sv32[bestc];
        fidx[s + n] = sidx[s + bestc];
        fcoef[s + n] = __fmul_rn(__fmul_rn(hv, hv), hv);
      }
    }
  }
  __syncthreads();

  // index-ascending placement into LDS (indices unique -> exact permutation)
  if (tid < TOPK_K) {
    int myi = fidx[tid];
    float myc = fcoef[tid];
    int rank = 0;
#pragma unroll
    for (int j2 = 0; j2 < TOPK_K; ++j2)
      rank += (fidx[j2] < myi) ? 1 : 0;
    sIdx[rank] = myi;
    sCf[rank] = myc;
  }
  __syncthreads();

  // sparse gather from fp16 W2T: out[row][:] = sum_j coef_j * W2T[idx_j][:] + b2
  float4 acc = {0.f, 0.f, 0.f, 0.f};
  for (int j = 0; j < TOPK_K; ++j) {
    const f16x4 w = *reinterpret_cast<const f16x4*>(w2t + (size_t)sIdx[j] * HIDDEN + tid * 4);
    float cf = sCf[j];
    acc.x = __builtin_fmaf(cf, (float)w[0], acc.x);
    acc.y = __builtin_fmaf(cf, (float)w[1], acc.y);
    acc.z = __builtin_fmaf(cf, (float)w[2], acc.z);
    acc.w = __builtin_fmaf(cf, (float)w[3], acc.w);
  }
  const float4 bb = reinterpret_cast<const float4*>(b2)[tid];
  acc.x += bb.x; acc.y += bb.y; acc.z += bb.z; acc.w += bb.w;
  reinterpret_cast<float4*>(out)[(size_t)row * (HIDDEN / 4) + tid] = acc;
}

// ------------------------------------------------- launch
extern "C" void kernel_launch(void* const* d_in, const int* in_sizes, int n_in,
                              void* d_out, int out_size, void* d_ws, size_t ws_size,
                              hipStream_t stream) {
  (void)in_sizes; (void)n_in; (void)out_size; (void)ws_size;
  const float* x  = (const float*)d_in[0];
  const float* W1 = (const float*)d_in[1];
  const float* b1 = (const float*)d_in[2];
  const float* W2 = (const float*)d_in[3];
  const float* b2 = (const float*)d_in[4];
  float* out = (float*)d_out;

  // workspace layout (~59 MB total)
  f16* xh = (f16*)d_ws;                                           // 16.78 MB
  f16* wh = xh + (size_t)NROWS * HIDDEN;                          //  8.39 MB
  f16* w2t = wh + (size_t)FFN * HIDDEN;                           //  8.39 MB
  u64* ckeys = (u64*)(w2t + (size_t)FFN * HIDDEN);                // 16.78 MB
  float* cvals = (float*)(ckeys + (size_t)NROWS * CCAP);          //  8.39 MB
  int* cnt = (int*)(cvals + (size_t)NROWS * CCAP);                //  32 KB

  hipMemsetAsync(cnt, 0, NROWS * sizeof(int), stream);
  prep_kernel<<<6144, 256, 0, stream>>>(x, W1, W2, xh, wh, w2t);
  gemm_topk_fused<<<dim3(NROWS / BM, FFN / BN), 256, 0, stream>>>(xh, wh, b1, ckeys, cvals, cnt);
  topk_scatter<<<NROWS, 256, 0, stream>>>(ckeys, cvals, cnt, x, W1, b1, w2t, b2, out);
}

// Round 16
// 295.079 us; speedup vs baseline: 1.1479x; 1.1479x over previous
//
#include <hip/hip_runtime.h>
#include <hip/hip_bf16.h>
#include <stdint.h>

#define HIDDEN 1024
#define FFN    4096
#define NROWS  8192   // 4*2048
#define TOPK_K 32
#define NCAND  40
#define MU     3e-3f  // band >= 2.5x max fp16-approx error (1.2e-3)
#define KC     384    // OpenBLAS SGEMM_DEFAULT_Q (verified rounds 4-15)
#define CCAP   256    // candidate capacity (survivors ~125 +- 11; validated R5-R15)
#define T0     1.25f  // pre-filter threshold: 7.7 sigma below |h|_(40)

#define BM 128
#define BN 128
#define BK 32
#define NT (HIDDEN / BK)      // 32 K-tiles
#define BUFSZ (2 * BM * BK)   // f16 elems per ring slot (A+B) = 16 KB

typedef _Float16 f16;
typedef __attribute__((ext_vector_type(8))) _Float16 f16x8;
typedef __attribute__((ext_vector_type(4))) _Float16 f16x4;
typedef __attribute__((ext_vector_type(2))) _Float16 f16x2;
typedef __attribute__((ext_vector_type(4))) float f32x4;
typedef unsigned long long u64;
typedef unsigned int u32;

__device__ __forceinline__ void async_copy16(const void* g, void* l) {
  __builtin_amdgcn_global_load_lds((void __attribute__((address_space(1)))*)(g),
                                   (void __attribute__((address_space(3)))*)(l),
                                   16, 0, 0);
}

// ------------------------------------------------- fused preprocessing:
// blocks [0,2048): fp32->fp16 convert of x and W1 (grid-stride)
// blocks [2048,6144): W2 transpose tile -> f16 [4096][1024]
__global__ void prep_kernel(const float* __restrict__ x, const float* __restrict__ W1,
                            const float* __restrict__ W2,
                            f16* __restrict__ xh, f16* __restrict__ wh,
                            f16* __restrict__ w2t) {
  const int tid = threadIdx.x;
  if (blockIdx.x < 2048) {
    const int n4x = NROWS * HIDDEN / 4;
    const int n4w = FFN * HIDDEN / 4;
    int i = blockIdx.x * 256 + tid;
    int stride = 2048 * 256;
    for (; i < n4x + n4w; i += stride) {
      const float4 v = (i < n4x) ? reinterpret_cast<const float4*>(x)[i]
                                 : reinterpret_cast<const float4*>(W1)[i - n4x];
      f16x4 o = {(f16)v.x, (f16)v.y, (f16)v.z, (f16)v.w};
      if (i < n4x) reinterpret_cast<f16x4*>(xh)[i] = o;
      else         reinterpret_cast<f16x4*>(wh)[i - n4x] = o;
    }
  } else {
    __shared__ float tile[32][33];
    const int b = blockIdx.x - 2048;
    const int bx = (b & 127) * 32;          // FFN
    const int by = (b >> 7) * 32;           // HIDDEN
    const int tx = tid & 31, ty = tid >> 5; // 32 x 8
#pragma unroll
    for (int r = 0; r < 32; r += 8)
      tile[ty + r][tx] = W2[(size_t)(by + ty + r) * FFN + bx + tx];
    __syncthreads();
#pragma unroll
    for (int r = 0; r < 32; r += 8)
      w2t[(size_t)(bx + ty + r) * HIDDEN + by + tx] = (f16)tile[tx][ty + r];
  }
}

// ------------------------------------------------- GEMM1 + fused T0 filter
// EXACT R14 structure (best measured across 6 structures: 158-163 us):
// fp16 single-product, 128x128 tile, BK=32, 3-slot LDS ring (A+B, 48 KB ->
// 3 blocks/CU) with counted s_waitcnt vmcnt(8) + raw s_barrier; LDS
// chunk-swizzle (rule #21 both-sides, 0 conflicts verified R9-R15).
__global__ __launch_bounds__(256)
void gemm_topk_fused(const f16* __restrict__ xh,
                     const f16* __restrict__ wh,
                     const float* __restrict__ b1,
                     u64* __restrict__ ckeys, float* __restrict__ cvals,
                     int* __restrict__ cnt) {
  __shared__ __align__(16) f16 smem[3][BUFSZ];   // 48 KB

  const int tid = threadIdx.x;
  const int rowBase = blockIdx.x * BM;
  const int colBase = blockIdx.y * BN;

  const int wid = tid >> 6, lane = tid & 63;
  const int wr = (wid >> 1) * 64;       // wave row offset in tile
  const int wc = (wid & 1) * 64;        // wave col offset in tile
  const int lr = lane & 15;
  const int kch = lane >> 4;            // k-chunk 0..3 (8 f16 each)

  // staging: thread covers 16B; dest LDS = tid*16 bytes (linear, required)
  const int r0 = tid >> 2;              // 0..63
  const int r1 = r0 + 64;               // 64..127
  const int c = tid & 3;
  const int off0 = r0 * BK + c * 8;     // == tid*8 f16
  const int off1 = r1 * BK + c * 8;
  const int sw = (c ^ ((r0 >> 1) & 3)) * 8;   // inverse swizzle

  const size_t gA0 = (size_t)(rowBase + r0) * HIDDEN + sw;
  const size_t gA1 = (size_t)(rowBase + r1) * HIDDEN + sw;
  const size_t gB0 = (size_t)(colBase + r0) * HIDDEN + sw;
  const size_t gB1 = (size_t)(colBase + r1) * HIDDEN + sw;

  f32x4 acc[4][4];
  const f32x4 zero4 = {0.f, 0.f, 0.f, 0.f};
#pragma unroll
  for (int m = 0; m < 4; ++m)
#pragma unroll
    for (int n = 0; n < 4; ++n) acc[m][n] = zero4;

  // swizzled read offsets (row-dependent chunk XOR)
  int roffA[4], roffB[4];
#pragma unroll
  for (int m = 0; m < 4; ++m) {
    int row = wr + m * 16 + lr;
    roffA[m] = row * BK + ((kch ^ ((row >> 1) & 3)) << 3);
  }
#pragma unroll
  for (int n = 0; n < 4; ++n) {
    int row = wc + n * 16 + lr;
    roffB[n] = row * BK + ((kch ^ ((row >> 1) & 3)) << 3);
  }

#define STAGE(slot, kb)                                       \
  do {                                                        \
    f16* sA_ = smem[slot];                                    \
    f16* sB_ = smem[slot] + BM * BK;                          \
    async_copy16(xh + gA0 + (kb), sA_ + off0);                \
    async_copy16(xh + gA1 + (kb), sA_ + off1);                \
    async_copy16(wh + gB0 + (kb), sB_ + off0);                \
    async_copy16(wh + gB1 + (kb), sB_ + off1);                \
  } while (0)

#define COMPUTE(slot)                                         \
  do {                                                        \
    const f16* sA_ = smem[slot];                              \
    const f16* sB_ = smem[slot] + BM * BK;                    \
    f16x8 a[4], b[4];                                         \
    _Pragma("unroll")                                         \
    for (int m = 0; m < 4; ++m) a[m] = *(const f16x8*)(sA_ + roffA[m]); \
    _Pragma("unroll")                                         \
    for (int n = 0; n < 4; ++n) b[n] = *(const f16x8*)(sB_ + roffB[n]); \
    _Pragma("unroll")                                         \
    for (int m = 0; m < 4; ++m)                               \
      _Pragma("unroll")                                       \
      for (int n = 0; n < 4; ++n)                             \
        acc[m][n] = __builtin_amdgcn_mfma_f32_16x16x32_f16(a[m], b[n], acc[m][n], 0, 0, 0); \
  } while (0)

  // prologue: stage tiles 0 and 1
  STAGE(0, 0);
  STAGE(1, BK);

  for (int t = 0; t < NT - 2; ++t) {
    STAGE((t + 2) % 3, (t + 2) * BK);
    asm volatile("s_waitcnt vmcnt(8)\n\ts_barrier" ::: "memory");
    COMPUTE(t % 3);
    asm volatile("s_barrier" ::: "memory");   // protect slot (t-1)%3 reuse
  }
  asm volatile("s_waitcnt vmcnt(4)\n\ts_barrier" ::: "memory");
  COMPUTE((NT - 2) % 3);
  asm volatile("s_barrier" ::: "memory");
  asm volatile("s_waitcnt vmcnt(0)\n\ts_barrier" ::: "memory");
  COMPUTE((NT - 1) % 3);
#undef STAGE
#undef COMPUTE

  // epilogue: bias + T0 filter + compact append
  // C/D layout (verified m89/m91): col = lane&15, row = (lane>>4)*4 + reg
  const int ccol = lane & 15;
  const int crow = (lane >> 4) * 4;
#pragma unroll
  for (int n = 0; n < 4; ++n) {
    int col = colBase + wc + n * 16 + ccol;
    float bias = b1[col];
    u32 inv = 0xFFFFFFFFu - (u32)col;
#pragma unroll
    for (int m = 0; m < 4; ++m) {
      int rowb = rowBase + wr + m * 16 + crow;
#pragma unroll
      for (int j = 0; j < 4; ++j) {
        float val = acc[m][n][j] + bias;
        if (fabsf(val) >= T0) {
          int row = rowb + j;
          int pos = atomicAdd(&cnt[row], 1);
          if (pos < CCAP) {
            ckeys[(size_t)row * CCAP + pos] =
                ((u64)__float_as_uint(fabsf(val)) << 32) | (u64)inv;
            cvals[(size_t)row * CCAP + pos] = val;
          }
        }
      }
    }
  }
}

// ------------------------------------------------- per-row select + adjudicate
// Rank-select top-40, verified round-4..15 adjudication (MU-band classify,
// OpenBLAS kc=384 fp32-chain emulation, cube), index-ascending output to
// tidx/tcoef (gather is a separate, L2-optimized kernel).
__global__ __launch_bounds__(256)
void topk_select(const u64* __restrict__ ckeys, const float* __restrict__ cvals,
                 const int* __restrict__ cnt,
                 const float* __restrict__ x, const float* __restrict__ W1,
                 const float* __restrict__ b1,
                 int* __restrict__ tidx, float* __restrict__ tcoef) {
  const int row = blockIdx.x;
  const int tid = threadIdx.x;

  __shared__ u64 k_lds[CCAP];
  __shared__ float v_lds[CCAP];
  __shared__ float sval[NCAND];
  __shared__ int   sidx[NCAND];
  __shared__ int   sS, sB;
  __shared__ float sv32[NCAND];
  __shared__ int   fidx[TOPK_K];
  __shared__ float fcoef[TOPK_K];

  int c = cnt[row];
  c = c < CCAP ? c : CCAP;
  if (tid < c) {
    k_lds[tid] = ckeys[(size_t)row * CCAP + tid];
    v_lds[tid] = cvals[(size_t)row * CCAP + tid];
  }
  if (tid < NCAND) { sval[tid] = 0.f; sidx[tid] = 0x7FFF0000 + tid; }
  __syncthreads();

  // parallel rank-select (keys unique -> strict order)
  if (tid < c) {
    const u64 mine = k_lds[tid];
    int rank = 0;
    for (int j2 = 0; j2 < c; ++j2)
      rank += (k_lds[j2] > mine) ? 1 : 0;
    if (rank < NCAND) {
      sval[rank] = v_lds[tid];
      sidx[rank] = (int)(0xFFFFFFFFu - (u32)(mine & 0xFFFFFFFFull));
    }
  }
  __syncthreads();

  // classify: sure-in prefix (> t+MU) vs boundary band [t-MU, t+MU]
  if (tid == 0) {
    float t = fabsf(sval[TOPK_K - 1]);
    int s = 0;
    while (s < TOPK_K - 1 && fabsf(sval[s]) > t + MU) ++s;
    int e = s;
    while (e < NCAND && fabsf(sval[e]) >= t - MU) ++e;
    sS = s;
    sB = e - s;       // >= 1 always (slot 31 is in the band)
  }
  __syncthreads();
  const int s = sS, nb = sB;

  // OpenBLAS-sgemm rounding emulation for boundary candidates
  if (nb > 1 && tid < nb) {
    const int fi = sidx[s + tid];
    const float* xr = x + (size_t)row * HIDDEN;
    const float* w1r = W1 + (size_t)fi * HIDDEN;
    float p0 = 0.0f, p1 = 0.0f, p2 = 0.0f;
    for (int k2 = 0; k2 < KC; ++k2)
      p0 = __builtin_fmaf(xr[k2], w1r[k2], p0);
    for (int k2 = KC; k2 < 2 * KC; ++k2)
      p1 = __builtin_fmaf(xr[k2], w1r[k2], p1);
    for (int k2 = 2 * KC; k2 < HIDDEN; ++k2)
      p2 = __builtin_fmaf(xr[k2], w1r[k2], p2);
    float acc = __fadd_rn(__fadd_rn(p0, p1), p2);   // C += panel merges
    sv32[tid] = __fadd_rn(acc, b1[fi]);
  }
  __syncthreads();

  if (tid == 0) {
    for (int k2 = 0; k2 < TOPK_K; ++k2) {
      fidx[k2] = sidx[k2];
      float hv = sval[k2];
      fcoef[k2] = __fmul_rn(__fmul_rn(hv, hv), hv);
    }
    if (nb > 1) {
      int need = TOPK_K - s;
      u64 used = 0;
      for (int n = 0; n < need; ++n) {
        int bestc = -1;
        u64 bestk = 0;
        for (int c2 = 0; c2 < nb; ++c2) {
          if (used & (1ull << c2)) continue;
          unsigned abv = __float_as_uint(fabsf(sv32[c2]));
          u64 kk2 = ((u64)abv << 32) | (u64)(0xFFFFFFFFu - (unsigned)sidx[s + c2]);
          if (bestc < 0 || kk2 > bestk) { bestk = kk2; bestc = c2; }
        }
        used |= 1ull << bestc;
        float hv = sv32[bestc];
        fidx[s + n] = sidx[s + bestc];
        fcoef[s + n] = __fmul_rn(__fmul_rn(hv, hv), hv);
      }
    }
  }
  __syncthreads();

  // index-ascending placement (indices unique -> exact permutation)
  if (tid < TOPK_K) {
    int myi = fidx[tid];
    float myc = fcoef[tid];
    int rank = 0;
#pragma unroll
    for (int j2 = 0; j2 < TOPK_K; ++j2)
      rank += (fidx[j2] < myi) ? 1 : 0;
    tidx[(size_t)row * TOPK_K + rank] = myi;
    tcoef[(size_t)row * TOPK_K + rank] = myc;
  }
}

// ------------------------------------------------- gather: out = sum coef*W2T[idx] + b2
// Column-halved + phase-ordered: bids [0,8192) do cols [0,512), bids
// [8192,16384) do cols [512,1024). Each phase's W2T working set = 4 MB
// (f16) = per-XCD-L2-resident; round-robin dispatch runs phase 0 (mostly)
// before phase 1 -> gather at L2 speed instead of L3.
__global__ __launch_bounds__(256)
void gather_kernel(const int* __restrict__ tidx, const float* __restrict__ tcoef,
                   const f16* __restrict__ w2t, const float* __restrict__ b2,
                   float* __restrict__ out) {
  const int bid = blockIdx.x;
  const int row = bid & (NROWS - 1);
  const int half = bid >> 13;            // 0 or 1
  const int tid = threadIdx.x;
  const int colBase = half * (HIDDEN / 2);
  const int col = colBase + tid * 2;     // 2 f16 per thread

  __shared__ int sIdx[TOPK_K];
  __shared__ float sCf[TOPK_K];
  if (tid < TOPK_K) {
    sIdx[tid] = tidx[(size_t)row * TOPK_K + tid];
    sCf[tid] = tcoef[(size_t)row * TOPK_K + tid];
  }
  __syncthreads();

  float ax = 0.f, ay = 0.f;
  // 8-way unrolled independent loads for ILP (TOPK_K = 32 = 4 groups of 8)
#pragma unroll
  for (int g = 0; g < TOPK_K; g += 8) {
    f16x2 w[8];
    float cf[8];
#pragma unroll
    for (int u = 0; u < 8; ++u) {
      w[u] = *reinterpret_cast<const f16x2*>(w2t + (size_t)sIdx[g + u] * HIDDEN + col);
      cf[u] = sCf[g + u];
    }
#pragma unroll
    for (int u = 0; u < 8; ++u) {
      ax = __builtin_fmaf(cf[u], (float)w[u][0], ax);
      ay = __builtin_fmaf(cf[u], (float)w[u][1], ay);
    }
  }
  float2 o;
  o.x = ax + b2[col];
  o.y = ay + b2[col + 1];
  reinterpret_cast<float2*>(out)[((size_t)row * HIDDEN + col) / 2] = o;
}

// ------------------------------------------------- launch
extern "C" void kernel_launch(void* const* d_in, const int* in_sizes, int n_in,
                              void* d_out, int out_size, void* d_ws, size_t ws_size,
                              hipStream_t stream) {
  (void)in_sizes; (void)n_in; (void)out_size; (void)ws_size;
  const float* x  = (const float*)d_in[0];
  const float* W1 = (const float*)d_in[1];
  const float* b1 = (const float*)d_in[2];
  const float* W2 = (const float*)d_in[3];
  const float* b2 = (const float*)d_in[4];
  float* out = (float*)d_out;

  // workspace layout (~61 MB total)
  f16* xh = (f16*)d_ws;                                           // 16.78 MB
  f16* wh = xh + (size_t)NROWS * HIDDEN;                          //  8.39 MB
  f16* w2t = wh + (size_t)FFN * HIDDEN;                           //  8.39 MB
  u64* ckeys = (u64*)(w2t + (size_t)FFN * HIDDEN);                // 16.78 MB
  float* cvals = (float*)(ckeys + (size_t)NROWS * CCAP);          //  8.39 MB
  int* cnt = (int*)(cvals + (size_t)NROWS * CCAP);                //  32 KB
  int* tidx = cnt + NROWS;                                        //  1.05 MB
  float* tcoef = (float*)(tidx + (size_t)NROWS * TOPK_K);         //  1.05 MB

  hipMemsetAsync(cnt, 0, NROWS * sizeof(int), stream);
  prep_kernel<<<6144, 256, 0, stream>>>(x, W1, W2, xh, wh, w2t);
  gemm_topk_fused<<<dim3(NROWS / BM, FFN / BN), 256, 0, stream>>>(xh, wh, b1, ckeys, cvals, cnt);
  topk_select<<<NROWS, 256, 0, stream>>>(ckeys, cvals, cnt, x, W1, b1, tidx, tcoef);
  gather_kernel<<<2 * NROWS, 256, 0, stream>>>(tidx, tcoef, w2t, b2, out);
}